// Round 8
// baseline (218.096 us; speedup 1.0000x reference)
//
#include <hip/hip_runtime.h>

// Bidirectional chamfer, B=4, N=M=5000, D=3, fp32.
// R8 = R6 structure (prep + single-stage 80KB LDS, one barrier, barrier-free
// main loop) + packed fp32 (v_pk_fma_f32 via float2 ext-vectors) + the R7
// spill fix: __launch_bounds__(1024,4) raises the VGPR cap to 128 (1 block/CU
// = 4 waves/EU), so the ~75 live per-lane floats stay in registers.
// Prep writes SoA (X|Y|Z|W per slice) so staging is coalesced dwordx4 ->
// ds_write_b128 with no scatter and no in-kernel norm pass.

#define BB      4
#define NP      5000
#define NPT     5120               // padded targets (sentinels)
#define THREADS 1024
#define WAVES   16
#define QW      10                 // queries per wave
#define QPB     (WAVES * QW)       // 160 queries per block
#define XBLKS   32                 // 32*160 = 5120 >= 5000 (masked tail)
#define GRID    (XBLKS * 2 * BB)   // 256 blocks = 1 per CU
#define NF4     (NPT / 4)          // 1280 float4 per SoA array
#define KITER   (NF4 / 64)         // 20 iterations, 4 targets/lane each
#define BIGF    3.0e38f

typedef float v2f __attribute__((ext_vector_type(2)));

// SoA slices: slice sb = s*4+b (s: 0=pred 1=gt) occupies 4*NPT floats:
// X[NPT] | Y[NPT] | Z[NPT] | W[NPT] (W=|p|^2; sentinel X=Y=Z=0,W=BIGF).
__global__ __launch_bounds__(256) void dl_prep_kernel(
    const float* __restrict__ pred, const float* __restrict__ gt,
    float* __restrict__ soa) {
    const int idx = blockIdx.x * 256 + threadIdx.x;   // 0 .. 8*NPT-1
    if (idx >= 8 * NPT) return;
    const int j  = idx % NPT;
    const int sb = idx / NPT;
    const int b  = sb & 3;
    const float* src = (sb >> 2) ? gt : pred;
    float x = 0.f, y = 0.f, z = 0.f, w = BIGF;
    if (j < NP) {
        const float* p = src + ((size_t)b * NP + j) * 3;
        x = p[0]; y = p[1]; z = p[2];
        w = x * x + y * y + z * z;
    }
    float* base = soa + (size_t)sb * 4 * NPT;
    base[j]           = x;
    base[NPT + j]     = y;
    base[2 * NPT + j] = z;
    base[3 * NPT + j] = w;
}

__global__ __launch_bounds__(THREADS, 4) void dl_chamfer_kernel(
    const float* __restrict__ soa,
    float* __restrict__ partials,      // [GRID]
    unsigned* __restrict__ counter,    // zeroed via memsetAsync
    float* __restrict__ out) {
    const int qblk = blockIdx.x;            // 0..31
    const int bz   = blockIdx.y;            // 0..7
    const int b    = bz >> 1;
    const int dir  = bz & 1;
    const float* qsl = soa + (size_t)(dir * 4 + b) * 4 * NPT;
    const float* tsl = soa + (size_t)((1 - dir) * 4 + b) * 4 * NPT;

    const int lane = threadIdx.x & 63;
    const int wave = __builtin_amdgcn_readfirstlane(threadIdx.x >> 6);

    // ---- stage all 4 SoA arrays (80 KB): 5 coalesced dwordx4 per thread
    __shared__ float4 tg4[4 * NF4];    // X4 | Y4 | Z4 | W4
    const float4* tsl4 = (const float4*)tsl;
    #pragma unroll
    for (int i = 0; i < (4 * NF4) / THREADS; ++i) {
        const int e = i * THREADS + threadIdx.x;
        tg4[e] = tsl4[e];
    }

    // ---- this wave's 10 queries (wave-uniform addresses -> SGPRs)
    float qx[QW], qy[QW], qz[QW], q2[QW];
    v2f m01[QW], m23[QW];
    const int qbase = qblk * QPB + wave * QW;
    #pragma unroll
    for (int r = 0; r < QW; ++r) {
        const int qi = (qbase + r < NP) ? (qbase + r) : 0;
        qx[r] = -2.0f * qsl[qi];
        qy[r] = -2.0f * qsl[NPT + qi];
        qz[r] = -2.0f * qsl[2 * NPT + qi];
        q2[r] = qsl[3 * NPT + qi];
        m01[r] = (v2f){BIGF, BIGF}; m23[r] = (v2f){BIGF, BIGF};
    }
    __syncthreads();   // the ONLY barrier before the main loop

    // ---- barrier-free main loop: 4 ds_read_b128 -> 4 targets/lane/iter
    const float4* X4 = tg4;
    const float4* Y4 = tg4 + NF4;
    const float4* Z4 = tg4 + 2 * NF4;
    const float4* W4 = tg4 + 3 * NF4;
    #pragma unroll 2
    for (int k = 0; k < KITER; ++k) {
        const int e = k * 64 + lane;
        const float4 xv = X4[e], yv = Y4[e], zv = Z4[e], wv = W4[e];
        const v2f x01 = {xv.x, xv.y}, x23 = {xv.z, xv.w};
        const v2f y01 = {yv.x, yv.y}, y23 = {yv.z, yv.w};
        const v2f z01 = {zv.x, zv.y}, z23 = {zv.z, zv.w};
        const v2f w01 = {wv.x, wv.y}, w23 = {wv.z, wv.w};
        #pragma unroll
        for (int r = 0; r < QW; ++r) {
            // |g|^2 - 2 q.g : three v_pk_fma_f32 per target pair
            v2f d01 = z01 * qz[r] + w01;
            d01 = y01 * qy[r] + d01;
            d01 = x01 * qx[r] + d01;
            v2f d23 = z23 * qz[r] + w23;
            d23 = y23 * qy[r] + d23;
            d23 = x23 * qx[r] + d23;
            m01[r].x = fminf(m01[r].x, d01.x);
            m01[r].y = fminf(m01[r].y, d01.y);
            m23[r].x = fminf(m23[r].x, d23.x);
            m23[r].y = fminf(m23[r].y, d23.y);
        }
    }

    // ---- fold 4 partial mins, then cross-lane butterfly
    float m[QW];
    #pragma unroll
    for (int r = 0; r < QW; ++r) {
        float v = fminf(fminf(m01[r].x, m01[r].y), fminf(m23[r].x, m23[r].y));
        #pragma unroll
        for (int off = 1; off < 64; off <<= 1)
            v = fminf(v, __shfl_xor(v, off, 64));
        m[r] = v;
    }

    // ---- per-wave row sums (mask padded queries), then block sum
    __shared__ float wsum[WAVES];
    if (lane == 0) {
        float s = 0.0f;
        #pragma unroll
        for (int r = 0; r < QW; ++r) {
            const float c = fmaxf(q2[r] + m[r], 0.0f);
            s += (qbase + r < NP) ? c : 0.0f;
        }
        wsum[wave] = s;
    }
    __syncthreads();

    const int bid = blockIdx.y * XBLKS + blockIdx.x;
    __shared__ unsigned lastFlag;
    if (threadIdx.x == 0) {
        float s = 0.0f;
        #pragma unroll
        for (int w = 0; w < WAVES; ++w) s += wsum[w];
        partials[bid] = s;
        __threadfence();
        lastFlag = (atomicAdd(counter, 1u) == GRID - 1) ? 1u : 0u;
    }
    __syncthreads();

    // ---- last-block finalize: sum 256 partials
    if (lastFlag) {
        __threadfence();
        float s = 0.0f;
        for (int i = threadIdx.x; i < GRID; i += THREADS)
            s += __hip_atomic_load((const float*)partials + i, __ATOMIC_RELAXED,
                                   __HIP_MEMORY_SCOPE_AGENT);
        #pragma unroll
        for (int off = 32; off > 0; off >>= 1)
            s += __shfl_down(s, off, 64);
        if (lane == 0) wsum[wave] = s;   // reuse wsum (barrier above)
        __syncthreads();
        if (threadIdx.x == 0) {
            float t = 0.0f;
            #pragma unroll
            for (int w = 0; w < WAVES; ++w) t += wsum[w];
            out[0] = t / (float)(BB * NP);
        }
    }
}

extern "C" void kernel_launch(void* const* d_in, const int* in_sizes, int n_in,
                              void* d_out, int out_size, void* d_ws, size_t ws_size,
                              hipStream_t stream) {
    const float* pred = (const float*)d_in[0];
    const float* gt   = (const float*)d_in[1];
    float* soa        = (float*)d_ws;                    // 8*4*5120*4 B = 640 KB
    float* partials   = soa + 8 * 4 * NPT;               // 256 floats
    unsigned* counter = (unsigned*)(partials + GRID);    // 1 u32
    float* out        = (float*)d_out;

    hipMemsetAsync(counter, 0, sizeof(unsigned), stream);  // graph-legal
    dl_prep_kernel<<<dim3((8 * NPT + 255) / 256), 256, 0, stream>>>(
        pred, gt, soa);
    dl_chamfer_kernel<<<dim3(XBLKS, 2 * BB), THREADS, 0, stream>>>(
        soa, partials, counter, out);
}

// Round 9
// 84.776 us; speedup vs baseline: 2.5726x; 2.5726x over previous
//
#include <hip/hip_runtime.h>

// Bidirectional chamfer, B=4, N=M=5000, D=3, fp32.
// R9: R6 structure (prep->SoA, single-stage LDS, one barrier, barrier-free
// main loop, scalar fp32) with LDS cut to 78.2 KB (no sentinel padding,
// masked tail iter) so TWO 1024-thread blocks co-reside per CU:
// 32 waves/CU = 8 waves/SIMD, doubling latency hiding vs R6.
// Live per-lane state ~35 VGPRs -> fits the 64-VGPR @8-waves budget, no spill.

#define BB      4
#define NP      5000
#define SL      (4 * NP)           // floats per slice: X|Y|Z|W arrays
#define THREADS 1024
#define WAVES   16
#define QW      5                  // queries per wave
#define QPB     (WAVES * QW)       // 80 queries per block
#define XBLKS   64                 // 64*80 = 5120 >= 5000 (masked tail queries)
#define GRID    (XBLKS * 2 * BB)   // 512 blocks = exactly 2 per CU
#define NF4     (NP / 4)           // 1250 float4 per SoA array
#define KFULL   (NF4 / 64)         // 19 full iters (1216 float4)
#define BIGF    3.0e38f

// SoA slices: slice sb = s*4+b (s: 0=pred 1=gt): X[NP]|Y[NP]|Z[NP]|W[NP].
__global__ __launch_bounds__(256) void dl_prep_kernel(
    const float* __restrict__ pred, const float* __restrict__ gt,
    float* __restrict__ soa) {
    const int idx = blockIdx.x * 256 + threadIdx.x;   // 0 .. 8*NP-1
    if (idx >= 8 * NP) return;
    const int j  = idx % NP;
    const int sb = idx / NP;
    const int b  = sb & 3;
    const float* src = (sb >> 2) ? gt : pred;
    const float* p = src + ((size_t)b * NP + j) * 3;
    const float x = p[0], y = p[1], z = p[2];
    float* base = soa + (size_t)sb * SL;
    base[j]          = x;
    base[NP + j]     = y;
    base[2 * NP + j] = z;
    base[3 * NP + j] = x * x + y * y + z * z;
}

__global__ __launch_bounds__(THREADS) void dl_chamfer_kernel(
    const float* __restrict__ soa,
    float* __restrict__ partials,      // [GRID]
    unsigned* __restrict__ counter,    // zeroed via memsetAsync
    float* __restrict__ out) {
    const int qblk = blockIdx.x;            // 0..63
    const int bz   = blockIdx.y;            // 0..7
    const int b    = bz >> 1;
    const int dir  = bz & 1;
    const float* qsl = soa + (size_t)(dir * 4 + b) * SL;
    const float* tsl = soa + (size_t)((1 - dir) * 4 + b) * SL;

    const int lane = threadIdx.x & 63;
    const int wave = __builtin_amdgcn_readfirstlane(threadIdx.x >> 6);

    // ---- stage all 4 SoA arrays (78.2 KB): 5 coalesced dwordx4/thread
    __shared__ float4 tg4[4 * NF4];    // X4 | Y4 | Z4 | W4 (contiguous slice)
    const float4* tsl4 = (const float4*)tsl;
    for (int e = threadIdx.x; e < 4 * NF4; e += THREADS)
        tg4[e] = tsl4[e];

    // ---- this wave's 5 queries (wave-uniform addresses -> s_load/SGPRs)
    float qx[QW], qy[QW], qz[QW], q2[QW], m[QW];
    const int qbase = qblk * QPB + wave * QW;
    #pragma unroll
    for (int r = 0; r < QW; ++r) {
        const int qi = (qbase + r < NP) ? (qbase + r) : 0;
        qx[r] = -2.0f * qsl[qi];
        qy[r] = -2.0f * qsl[NP + qi];
        qz[r] = -2.0f * qsl[2 * NP + qi];
        q2[r] = qsl[3 * NP + qi];
        m[r]  = BIGF;
    }
    __syncthreads();   // the ONLY barrier before the main loop

    // ---- barrier-free main loop: 4 ds_read_b128 -> 4 targets/lane/iter
    const float4* X4 = tg4;
    const float4* Y4 = tg4 + NF4;
    const float4* Z4 = tg4 + 2 * NF4;
    const float4* W4 = tg4 + 3 * NF4;
    #pragma unroll 2
    for (int k = 0; k < KFULL; ++k) {
        const int e = k * 64 + lane;
        const float4 xv = X4[e], yv = Y4[e], zv = Z4[e], wv = W4[e];
        const float xs[4] = {xv.x, xv.y, xv.z, xv.w};
        const float ys[4] = {yv.x, yv.y, yv.z, yv.w};
        const float zs[4] = {zv.x, zv.y, zv.z, zv.w};
        const float ws[4] = {wv.x, wv.y, wv.z, wv.w};
        #pragma unroll
        for (int c = 0; c < 4; ++c) {
            #pragma unroll
            for (int r = 0; r < QW; ++r) {
                // |g|^2 - 2 q.g : 3 fma + min per pair
                float d = __builtin_fmaf(qz[r], zs[c], ws[c]);
                d = __builtin_fmaf(qy[r], ys[c], d);
                d = __builtin_fmaf(qx[r], xs[c], d);
                m[r] = fminf(m[r], d);
            }
        }
    }
    // tail: float4 indices 1216..1249 (34 lanes active) — exec-masked so
    // no lane ever reads past its array (no sentinels needed)
    {
        const int e = KFULL * 64 + lane;
        if (e < NF4) {
            const float4 xv = X4[e], yv = Y4[e], zv = Z4[e], wv = W4[e];
            const float xs[4] = {xv.x, xv.y, xv.z, xv.w};
            const float ys[4] = {yv.x, yv.y, yv.z, yv.w};
            const float zs[4] = {zv.x, zv.y, zv.z, zv.w};
            const float ws[4] = {wv.x, wv.y, wv.z, wv.w};
            #pragma unroll
            for (int c = 0; c < 4; ++c) {
                #pragma unroll
                for (int r = 0; r < QW; ++r) {
                    float d = __builtin_fmaf(qz[r], zs[c], ws[c]);
                    d = __builtin_fmaf(qy[r], ys[c], d);
                    d = __builtin_fmaf(qx[r], xs[c], d);
                    m[r] = fminf(m[r], d);
                }
            }
        }
    }

    // ---- cross-lane min butterfly (lanes covered disjoint targets)
    #pragma unroll
    for (int r = 0; r < QW; ++r) {
        float v = m[r];
        #pragma unroll
        for (int off = 1; off < 64; off <<= 1)
            v = fminf(v, __shfl_xor(v, off, 64));
        m[r] = v;
    }

    // ---- per-wave row sums (mask padded queries), then block sum
    __shared__ float wsum[WAVES];
    if (lane == 0) {
        float s = 0.0f;
        #pragma unroll
        for (int r = 0; r < QW; ++r) {
            const float c = fmaxf(q2[r] + m[r], 0.0f);
            s += (qbase + r < NP) ? c : 0.0f;
        }
        wsum[wave] = s;
    }
    __syncthreads();

    const int bid = blockIdx.y * XBLKS + blockIdx.x;
    __shared__ unsigned lastFlag;
    if (threadIdx.x == 0) {
        float s = 0.0f;
        #pragma unroll
        for (int w = 0; w < WAVES; ++w) s += wsum[w];
        partials[bid] = s;
        __threadfence();
        lastFlag = (atomicAdd(counter, 1u) == GRID - 1) ? 1u : 0u;
    }
    __syncthreads();

    // ---- last-block finalize: sum 512 partials
    if (lastFlag) {
        __threadfence();
        float s = 0.0f;
        for (int i = threadIdx.x; i < GRID; i += THREADS)
            s += __hip_atomic_load((const float*)partials + i, __ATOMIC_RELAXED,
                                   __HIP_MEMORY_SCOPE_AGENT);
        #pragma unroll
        for (int off = 32; off > 0; off >>= 1)
            s += __shfl_down(s, off, 64);
        if (lane == 0) wsum[wave] = s;   // reuse wsum (barrier above)
        __syncthreads();
        if (threadIdx.x == 0) {
            float t = 0.0f;
            #pragma unroll
            for (int w = 0; w < WAVES; ++w) t += wsum[w];
            out[0] = t / (float)(BB * NP);
        }
    }
}

extern "C" void kernel_launch(void* const* d_in, const int* in_sizes, int n_in,
                              void* d_out, int out_size, void* d_ws, size_t ws_size,
                              hipStream_t stream) {
    const float* pred = (const float*)d_in[0];
    const float* gt   = (const float*)d_in[1];
    float* soa        = (float*)d_ws;                    // 8*20000*4 B = 640 KB
    float* partials   = soa + 8 * SL;                    // 512 floats
    unsigned* counter = (unsigned*)(partials + GRID);    // 1 u32
    float* out        = (float*)d_out;

    hipMemsetAsync(counter, 0, sizeof(unsigned), stream);  // graph-legal
    dl_prep_kernel<<<dim3((8 * NP + 255) / 256), 256, 0, stream>>>(
        pred, gt, soa);
    dl_chamfer_kernel<<<dim3(XBLKS, 2 * BB), THREADS, 0, stream>>>(
        soa, partials, counter, out);
}

// Round 10
// 81.752 us; speedup vs baseline: 2.6678x; 1.0370x over previous
//
#include <hip/hip_runtime.h>

// Bidirectional chamfer, B=4, N=M=5000, D=3, fp32.
// R10: fused staging + wave-pair j-split at QW=10.
//  - 1024-thread blocks, 16 waves = 8 pairs; each pair owns 10 query rows.
//    Query values are wave-uniform -> live in SGPRs (R5/R6 evidence: VGPR=32),
//    so QW=10 costs no VGPRs. Per-lane VGPR state ~36 -> no spill at 8 w/SIMD.
//  - The two waves of a pair split the 1250 float4 targets (640/610): halves
//    LDS-read traffic vs R9 -> VALU-bound (10.4 us) instead of LDS-bound.
//  - Block stages raw float3 global -> SoA LDS (X|Y|Z|W, 78.1 KB) itself:
//    no prep kernel. 80.7 KB total LDS -> 2 blocks/CU = 32 waves/CU.
//  - Tiny 1-block reduce kernel afterwards (dispatch-boundary coherence ->
//    plain loads safe; no counter, no memset).

#define BB      4
#define NP      5000
#define THREADS 1024
#define WAVES   16
#define PAIRS   8                  // wave pairs per block
#define QW      10                 // query rows per pair
#define QPB     (PAIRS * QW)       // 80 rows per block
#define XBLKS   63                 // 63*80 = 5040 >= 5000 (tail rows masked)
#define GRID    (XBLKS * 2 * BB)   // 504 blocks (~2 per CU)
#define NF4     (NP / 4)           // 1250 float4 per SoA array
#define ESPLIT  640                // wave jh=0: [0,640), jh=1: [640,1250)
#define BIGF    3.0e38f

__global__ __launch_bounds__(THREADS) void dl_chamfer_kernel(
    const float* __restrict__ pred, const float* __restrict__ gt,
    float* __restrict__ partials) {
    const int qblk = blockIdx.x;            // 0..62
    const int bz   = blockIdx.y;            // 0..7
    const int b    = bz >> 1;
    const int dir  = bz & 1;
    const float* qsrc = dir ? gt   : pred;
    const float* tsrc = dir ? pred : gt;

    const int lane = threadIdx.x & 63;
    const int wave = __builtin_amdgcn_readfirstlane(threadIdx.x >> 6);
    const int pair = wave >> 1;
    const int jh   = wave & 1;

    // LDS: X[NP] | Y[NP] | Z[NP] | W[NP] | mshare[16*QW] | wsum[PAIRS]
    __shared__ float smem[4 * NP + WAVES * QW + PAIRS];
    float* mshare = smem + 4 * NP;
    float* wsum   = smem + 4 * NP + WAVES * QW;

    // ---- stage raw target float3 (coalesced dwordx4), scatter to SoA LDS
    const float4* tb4 = (const float4*)(tsrc + (size_t)b * NP * 3); // 3750 f4
    for (int f = threadIdx.x; f < (3 * NP) / 4; f += THREADS) {
        const float4 v = tb4[f];
        const float vv[4] = {v.x, v.y, v.z, v.w};
        const int i0 = 4 * f;
        #pragma unroll
        for (int c = 0; c < 4; ++c) {
            const int i = i0 + c;
            const int j = i / 3;            // magic-mul div
            smem[(i - 3 * j) * NP + j] = vv[c];
        }
    }

    // ---- this pair's 10 query rows (wave-uniform -> SGPRs)
    float qx[QW], qy[QW], qz[QW], m[QW];
    const int qbase = qblk * QPB + pair * QW;
    const float* qb = qsrc + (size_t)b * NP * 3;
    #pragma unroll
    for (int r = 0; r < QW; ++r) {
        const int qi = (qbase + r < NP) ? (qbase + r) : 0;
        qx[r] = -2.0f * qb[3 * qi];
        qy[r] = -2.0f * qb[3 * qi + 1];
        qz[r] = -2.0f * qb[3 * qi + 2];
        m[r]  = BIGF;
    }
    __syncthreads();

    // ---- norm pass: W[j] = |g_j|^2 (conflict-free strided b32)
    for (int j = threadIdx.x; j < NP; j += THREADS) {
        const float x = smem[j], y = smem[NP + j], z = smem[2 * NP + j];
        smem[3 * NP + j] = x * x + y * y + z * z;
    }
    __syncthreads();

    // ---- barrier-free main loop: this wave's half of the targets
    const float4* X4 = (const float4*)smem;
    const float4* Y4 = X4 + NF4;
    const float4* Z4 = X4 + 2 * NF4;
    const float4* W4 = X4 + 3 * NF4;
    const int ebase = jh ? ESPLIT : 0;
    const int eend  = jh ? NF4 : ESPLIT;
    #pragma unroll 2
    for (int k = 0; k < 10; ++k) {
        const int e = ebase + k * 64 + lane;
        if (e < eend) {
            const float4 xv = X4[e], yv = Y4[e], zv = Z4[e], wv = W4[e];
            const float xs[4] = {xv.x, xv.y, xv.z, xv.w};
            const float ys[4] = {yv.x, yv.y, yv.z, yv.w};
            const float zs[4] = {zv.x, zv.y, zv.z, zv.w};
            const float ws[4] = {wv.x, wv.y, wv.z, wv.w};
            #pragma unroll
            for (int c = 0; c < 4; ++c) {
                #pragma unroll
                for (int r = 0; r < QW; ++r) {
                    // |g|^2 - 2 q.g : 3 fma + min per pair
                    float d = __builtin_fmaf(qz[r], zs[c], ws[c]);
                    d = __builtin_fmaf(qy[r], ys[c], d);
                    d = __builtin_fmaf(qx[r], xs[c], d);
                    m[r] = fminf(m[r], d);
                }
            }
        }
    }

    // ---- cross-lane min butterfly (lanes covered disjoint targets)
    #pragma unroll
    for (int r = 0; r < QW; ++r) {
        float v = m[r];
        #pragma unroll
        for (int off = 1; off < 64; off <<= 1)
            v = fminf(v, __shfl_xor(v, off, 64));
        m[r] = v;
    }

    // ---- cross-wave (pair) combine + row sums
    if (lane == 0) {
        #pragma unroll
        for (int r = 0; r < QW; ++r) mshare[wave * QW + r] = m[r];
    }
    __syncthreads();
    if (jh == 0 && lane == 0) {
        float s = 0.0f;
        #pragma unroll
        for (int r = 0; r < QW; ++r) {
            const float q2 = 0.25f * (qx[r] * qx[r] + qy[r] * qy[r] +
                                      qz[r] * qz[r]);
            const float mm = fminf(m[r], mshare[(wave + 1) * QW + r]);
            const float c  = fmaxf(q2 + mm, 0.0f);
            s += (qbase + r < NP) ? c : 0.0f;
        }
        wsum[pair] = s;
    }
    __syncthreads();
    if (threadIdx.x == 0) {
        float s = 0.0f;
        #pragma unroll
        for (int p = 0; p < PAIRS; ++p) s += wsum[p];
        partials[blockIdx.y * XBLKS + blockIdx.x] = s;
    }
}

__global__ __launch_bounds__(256) void dl_reduce_kernel(
    const float* __restrict__ partials, float* __restrict__ out) {
    // separate dispatch: release-at-end/acquire-at-start makes plain loads safe
    float s = 0.0f;
    for (int i = threadIdx.x; i < GRID; i += 256)
        s += partials[i];
    #pragma unroll
    for (int off = 32; off > 0; off >>= 1)
        s += __shfl_down(s, off, 64);
    __shared__ float ws[4];
    const int wave = threadIdx.x >> 6;
    if ((threadIdx.x & 63) == 0) ws[wave] = s;
    __syncthreads();
    if (threadIdx.x == 0)
        out[0] = (ws[0] + ws[1] + ws[2] + ws[3]) / (float)(BB * NP);
}

extern "C" void kernel_launch(void* const* d_in, const int* in_sizes, int n_in,
                              void* d_out, int out_size, void* d_ws, size_t ws_size,
                              hipStream_t stream) {
    const float* pred = (const float*)d_in[0];
    const float* gt   = (const float*)d_in[1];
    float* partials   = (float*)d_ws;        // GRID floats
    float* out        = (float*)d_out;

    dl_chamfer_kernel<<<dim3(XBLKS, 2 * BB), THREADS, 0, stream>>>(
        pred, gt, partials);
    dl_reduce_kernel<<<1, 256, 0, stream>>>(partials, out);
}